// Round 1
// baseline (879.560 us; speedup 1.0000x reference)
//
#include <hip/hip_runtime.h>
#include <math.h>

// Problem constants (from reference): N=8192, D=16, C=8, R=64
#define D_ 16
#define C_ 8
#define R_ 64
#define KTOT 152          // C + D*(C+1) = 8 + 16*9

// Output layout (concatenated flat, return order):
//   new_emb      : N*R           floats at offset 0
//   new_node_mem : N*C*R         floats at offset N*R
//   new_rel_mem  : N*C*R         floats at offset N*R + N*C*R

__global__ __launch_bounds__(256)
void memagg_kernel(const float* __restrict__ curr_emb,
                   const float* __restrict__ alpha,
                   const float* __restrict__ msg,
                   const float* __restrict__ curr_node_mem,
                   const float* __restrict__ curr_rel_mem,
                   const float* __restrict__ nei_node_mem,
                   const float* __restrict__ nei_rel_mem,
                   const float* __restrict__ head_rel_emb,
                   const float* __restrict__ head_emb,
                   float* __restrict__ out,
                   int N)
{
    __shared__ float s_emb[R_];
    __shared__ float s_scores[KTOT];
    __shared__ int   s_topk[C_];

    const int n   = blockIdx.x;
    const int tid = threadIdx.x;

    // ---------------- Phase 0: new_emb = sum_d alpha[n,d]*msg[n,d,:] + curr_emb[n,0,:]
    // numpy einsum: sequential accumulation over d in f32, no FMA contraction.
    if (tid < R_) {
        const int r = tid;
        const float* arow = alpha + (size_t)n * D_;
        const float* mrow = msg + (size_t)n * D_ * R_ + r;
        float acc = 0.0f;
        #pragma unroll
        for (int d = 0; d < D_; ++d) {
            acc = __fadd_rn(acc, __fmul_rn(arow[d], mrow[(size_t)d * R_]));
        }
        float ce = curr_emb[(size_t)n * D_ * R_ + r];   // [n][0][r]
        float ne = __fadd_rn(acc, ce);
        s_emb[r] = ne;
        out[(size_t)n * R_ + r] = ne;
    }
    __syncthreads();

    // ---------------- Phase 1: 152 scores, numpy pairwise-sum order bitwise.
    // 8 lanes per row; lane j accumulates elements j, j+8, ..., j+56 sequentially,
    // then xor-tree combine = ((r0+r1)+(r2+r3)) + ((r4+r5)+(r6+r7)).
    {
        const int grp = tid >> 3;   // 0..31 : row group
        const int j8  = tid & 7;    // 0..7  : accumulator lane
        for (int k = grp; k < KTOT; k += 32) {
            const float* nptr;
            const float* rptr;
            const float* hptr = nullptr;   // head_rel_emb to add to rel
            if (k < C_) {
                size_t base = ((size_t)n * D_ * C_ + k) * R_;   // [n][0][k][:]
                nptr = curr_node_mem + base;
                rptr = curr_rel_mem + base;
            } else {
                int k2 = k - C_;
                int d  = k2 / 9;
                int jj = k2 - d * 9;
                size_t hb = ((size_t)n * D_ + d) * R_;
                if (jj < C_) {
                    size_t base = (((size_t)n * D_ + d) * C_ + jj) * R_;
                    nptr = nei_node_mem + base;
                    rptr = nei_rel_mem + base;
                    hptr = head_rel_emb + hb;
                } else {
                    nptr = head_emb + hb;
                    rptr = head_rel_emb + hb;
                }
            }
            float acc = 0.0f;
            #pragma unroll
            for (int t = 0; t < 8; ++t) {
                int i = j8 + t * 8;
                float nodev = nptr[i];
                float relv  = rptr[i];
                if (hptr) relv = __fadd_rn(relv, hptr[i]);
                float sumv = __fadd_rn(nodev, relv);
                float diff = __fsub_rn(sumv, s_emb[i]);
                float sq   = __fmul_rn(diff, diff);
                acc = __fadd_rn(acc, sq);
            }
            // combine across the 8 lanes (bitwise == numpy combine by commutativity)
            acc = __fadd_rn(acc, __shfl_xor(acc, 1, 64));
            acc = __fadd_rn(acc, __shfl_xor(acc, 2, 64));
            acc = __fadd_rn(acc, __shfl_xor(acc, 4, 64));
            if (j8 == 0) s_scores[k] = __fsqrt_rn(acc);  // IEEE sqrt, matches np
        }
    }
    __syncthreads();

    // ---------------- Phase 2: stable top-8 (descending score, ties -> smaller index)
    if (tid < 64) {
        float v0 = (tid       < KTOT) ? s_scores[tid]       : -INFINITY;
        float v1 = (tid + 64  < KTOT) ? s_scores[tid + 64]  : -INFINITY;
        float v2 = (tid + 128 < KTOT) ? s_scores[tid + 128] : -INFINITY;
        #pragma unroll
        for (int it = 0; it < C_; ++it) {
            float bv = v0; int bi = tid;
            if (v1 > bv) { bv = v1; bi = tid + 64; }
            if (v2 > bv) { bv = v2; bi = tid + 128; }
            #pragma unroll
            for (int m = 1; m < 64; m <<= 1) {
                float ov = __shfl_xor(bv, m, 64);
                int   oi = __shfl_xor(bi, m, 64);
                if (ov > bv || (ov == bv && oi < bi)) { bv = ov; bi = oi; }
            }
            if (tid == 0) s_topk[it] = bi;
            if      (bi == tid)       v0 = -INFINITY;
            else if (bi == tid + 64)  v1 = -INFINITY;
            else if (bi == tid + 128) v2 = -INFINITY;
        }
    }
    __syncthreads();

    // ---------------- Phase 3: gather selected rows (flat index crosses n!)
    // 16 groups of 16 lanes; group = (j, node/rel); lane q handles float4 [4q..4q+3]
    {
        const int g16  = tid >> 4;    // 0..15
        const int q    = tid & 15;    // 0..15
        const int j    = g16 >> 1;    // 0..7 output slot
        const bool rel = (g16 & 1) != 0;

        const int t  = s_topk[j];
        const int f  = n * C_ + t;        // reference: arange(n)*c + topkind
        const int n2 = f / KTOT;
        const int k  = f - n2 * KTOT;

        const size_t o_node = (size_t)N * R_;
        const size_t o_rel  = o_node + (size_t)N * C_ * R_;

        float4 val;
        if (k < C_) {
            size_t base = ((size_t)n2 * D_ * C_ + k) * R_;
            const float4* p = (const float4*)((rel ? curr_rel_mem : curr_node_mem) + base);
            val = p[q];
        } else {
            int k2 = k - C_;
            int d  = k2 / 9;
            int jj = k2 - d * 9;
            size_t hb = ((size_t)n2 * D_ + d) * R_;
            if (jj < C_) {
                size_t base = (((size_t)n2 * D_ + d) * C_ + jj) * R_;
                if (!rel) {
                    val = ((const float4*)(nei_node_mem + base))[q];
                } else {
                    float4 a = ((const float4*)(nei_rel_mem + base))[q];
                    float4 h = ((const float4*)(head_rel_emb + hb))[q];
                    val.x = __fadd_rn(a.x, h.x);
                    val.y = __fadd_rn(a.y, h.y);
                    val.z = __fadd_rn(a.z, h.z);
                    val.w = __fadd_rn(a.w, h.w);
                }
            } else {
                const float4* p = (const float4*)((rel ? head_rel_emb : head_emb) + hb);
                val = p[q];
            }
        }
        float* dst = out + (rel ? o_rel : o_node) + ((size_t)n * C_ + j) * R_;
        ((float4*)dst)[q] = val;
    }
}

extern "C" void kernel_launch(void* const* d_in, const int* in_sizes, int n_in,
                              void* d_out, int out_size, void* d_ws, size_t ws_size,
                              hipStream_t stream) {
    const float* curr_emb      = (const float*)d_in[0];
    const float* alpha         = (const float*)d_in[1];
    const float* msg           = (const float*)d_in[2];
    const float* curr_node_mem = (const float*)d_in[3];
    const float* curr_rel_mem  = (const float*)d_in[4];
    const float* nei_node_mem  = (const float*)d_in[5];
    const float* nei_rel_mem   = (const float*)d_in[6];
    const float* head_rel_emb  = (const float*)d_in[7];
    const float* head_emb      = (const float*)d_in[8];
    float* out = (float*)d_out;

    const int N = in_sizes[1] / D_;   // alpha is (N, D, 1)

    memagg_kernel<<<N, 256, 0, stream>>>(curr_emb, alpha, msg,
                                         curr_node_mem, curr_rel_mem,
                                         nei_node_mem, nei_rel_mem,
                                         head_rel_emb, head_emb,
                                         out, N);
}

// Round 2
// 856.757 us; speedup vs baseline: 1.0266x; 1.0266x over previous
//
#include <hip/hip_runtime.h>
#include <math.h>

// Problem constants (from reference): N=8192, D=16, C=8, R=64
#define D_ 16
#define C_ 8
#define R_ 64
#define KTOT 152          // C + D*(C+1) = 8 + 16*9
#define SQ_STRIDE 68      // 64 + 4 pad: bank = 4*(k+i) mod 32 -> conflict-free b128

// Output layout (concatenated flat, return order):
//   new_emb      : N*R   at offset 0
//   new_node_mem : N*C*R at offset N*R
//   new_rel_mem  : N*C*R at offset N*R + N*C*R

__global__ __launch_bounds__(256)
void memagg_kernel(const float* __restrict__ curr_emb,
                   const float* __restrict__ alpha,
                   const float* __restrict__ msg,
                   const float* __restrict__ curr_node_mem,
                   const float* __restrict__ curr_rel_mem,
                   const float* __restrict__ nei_node_mem,
                   const float* __restrict__ nei_rel_mem,
                   const float* __restrict__ head_rel_emb,
                   const float* __restrict__ head_emb,
                   float* __restrict__ out,
                   int N)
{
    __shared__ float s_sq[KTOT * SQ_STRIDE];   // 41.3 KB: per-row squared diffs
    __shared__ float s_emb[R_];
    __shared__ float s_scores[KTOT];
    __shared__ int   s_topk[C_];

    const int n   = blockIdx.x;
    const int tid = threadIdx.x;

    // ---------------- Phase 0: new_emb = sum_d alpha[n,d]*msg[n,d,:] + curr_emb[n,0,:]
    // numpy einsum: sequential accumulation over d in f32, no FMA contraction.
    if (tid < R_) {
        const int r = tid;
        const float* arow = alpha + (size_t)n * D_;
        const float* mrow = msg + (size_t)n * D_ * R_ + r;
        float acc = 0.0f;
        #pragma unroll
        for (int d = 0; d < D_; ++d) {
            acc = __fadd_rn(acc, __fmul_rn(arow[d], mrow[(size_t)d * R_]));
        }
        float ce = curr_emb[(size_t)n * D_ * R_ + r];   // [n][0][r]
        float ne = __fadd_rn(acc, ce);
        s_emb[r] = ne;
        out[(size_t)n * R_ + r] = ne;
    }
    __syncthreads();

    // ---------------- Phase 1a: coalesced float4 staging of squared diffs.
    // 16 groups x 16 lanes; group handles rows k = g, g+16, ...
    // Per wave-instruction: 1 KB contiguous (4 rows x 256 B).
    {
        const int g = tid >> 4;     // 0..15 row group
        const int q = tid & 15;     // 0..15 float4 slot within row
        const float4 e4 = ((const float4*)s_emb)[q];
        for (int k = g; k < KTOT; k += 16) {
            const float* nptr;
            const float* rptr;
            const float* hptr = nullptr;
            if (k < C_) {
                size_t base = ((size_t)n * D_ * C_ + k) * R_;   // [n][0][k][:]
                nptr = curr_node_mem + base;
                rptr = curr_rel_mem + base;
            } else {
                int k2 = k - C_;
                int d  = k2 / 9;
                int jj = k2 - d * 9;
                size_t hb = ((size_t)n * D_ + d) * R_;
                if (jj < C_) {
                    size_t base = (((size_t)n * D_ + d) * C_ + jj) * R_;
                    nptr = nei_node_mem + base;
                    rptr = nei_rel_mem + base;
                    hptr = head_rel_emb + hb;
                } else {
                    nptr = head_emb + hb;
                    rptr = head_rel_emb + hb;
                }
            }
            float4 nodev = ((const float4*)nptr)[q];
            float4 relv  = ((const float4*)rptr)[q];
            if (hptr) {
                float4 h = ((const float4*)hptr)[q];
                relv.x = __fadd_rn(relv.x, h.x);
                relv.y = __fadd_rn(relv.y, h.y);
                relv.z = __fadd_rn(relv.z, h.z);
                relv.w = __fadd_rn(relv.w, h.w);
            }
            float4 sq;
            float dx = __fsub_rn(__fadd_rn(nodev.x, relv.x), e4.x);
            float dy = __fsub_rn(__fadd_rn(nodev.y, relv.y), e4.y);
            float dz = __fsub_rn(__fadd_rn(nodev.z, relv.z), e4.z);
            float dw = __fsub_rn(__fadd_rn(nodev.w, relv.w), e4.w);
            sq.x = __fmul_rn(dx, dx);
            sq.y = __fmul_rn(dy, dy);
            sq.z = __fmul_rn(dz, dz);
            sq.w = __fmul_rn(dw, dw);
            ((float4*)(s_sq + k * SQ_STRIDE))[q] = sq;
        }
    }
    __syncthreads();

    // ---------------- Phase 1b: one lane per row — exact numpy pairwise order.
    // r[j] = a[j]; for t=1..7: r[j] += a[j+8t]; then ((r0+r1)+(r2+r3))+((r4+r5)+(r6+r7))
    if (tid < KTOT) {
        const float4* row = (const float4*)(s_sq + tid * SQ_STRIDE);
        float4 c0 = row[0];
        float4 c1 = row[1];
        float r0 = c0.x, r1 = c0.y, r2 = c0.z, r3 = c0.w;
        float r4 = c1.x, r5 = c1.y, r6 = c1.z, r7 = c1.w;
        #pragma unroll
        for (int t = 1; t < 8; ++t) {
            float4 a = row[2 * t];
            float4 b = row[2 * t + 1];
            r0 = __fadd_rn(r0, a.x); r1 = __fadd_rn(r1, a.y);
            r2 = __fadd_rn(r2, a.z); r3 = __fadd_rn(r3, a.w);
            r4 = __fadd_rn(r4, b.x); r5 = __fadd_rn(r5, b.y);
            r6 = __fadd_rn(r6, b.z); r7 = __fadd_rn(r7, b.w);
        }
        float s = __fadd_rn(__fadd_rn(__fadd_rn(r0, r1), __fadd_rn(r2, r3)),
                            __fadd_rn(__fadd_rn(r4, r5), __fadd_rn(r6, r7)));
        s_scores[tid] = __fsqrt_rn(s);
    }
    __syncthreads();

    // ---------------- Phase 2: stable top-8 (descending score, ties -> smaller index)
    if (tid < 64) {
        float v0 = (tid       < KTOT) ? s_scores[tid]       : -INFINITY;
        float v1 = (tid + 64  < KTOT) ? s_scores[tid + 64]  : -INFINITY;
        float v2 = (tid + 128 < KTOT) ? s_scores[tid + 128] : -INFINITY;
        #pragma unroll
        for (int it = 0; it < C_; ++it) {
            float bv = v0; int bi = tid;
            if (v1 > bv) { bv = v1; bi = tid + 64; }
            if (v2 > bv) { bv = v2; bi = tid + 128; }
            #pragma unroll
            for (int m = 1; m < 64; m <<= 1) {
                float ov = __shfl_xor(bv, m, 64);
                int   oi = __shfl_xor(bi, m, 64);
                if (ov > bv || (ov == bv && oi < bi)) { bv = ov; bi = oi; }
            }
            if (tid == 0) s_topk[it] = bi;
            if      (bi == tid)       v0 = -INFINITY;
            else if (bi == tid + 64)  v1 = -INFINITY;
            else if (bi == tid + 128) v2 = -INFINITY;
        }
    }
    __syncthreads();

    // ---------------- Phase 3: gather selected rows (flat index crosses n!)
    {
        const int g16  = tid >> 4;    // 0..15
        const int q    = tid & 15;    // 0..15
        const int j    = g16 >> 1;    // 0..7 output slot
        const bool rel = (g16 & 1) != 0;

        const int t  = s_topk[j];
        const int f  = n * C_ + t;        // reference: arange(n)*c + topkind
        const int n2 = f / KTOT;
        const int k  = f - n2 * KTOT;

        const size_t o_node = (size_t)N * R_;
        const size_t o_rel  = o_node + (size_t)N * C_ * R_;

        float4 val;
        if (k < C_) {
            size_t base = ((size_t)n2 * D_ * C_ + k) * R_;
            const float4* p = (const float4*)((rel ? curr_rel_mem : curr_node_mem) + base);
            val = p[q];
        } else {
            int k2 = k - C_;
            int d  = k2 / 9;
            int jj = k2 - d * 9;
            size_t hb = ((size_t)n2 * D_ + d) * R_;
            if (jj < C_) {
                size_t base = (((size_t)n2 * D_ + d) * C_ + jj) * R_;
                if (!rel) {
                    val = ((const float4*)(nei_node_mem + base))[q];
                } else {
                    float4 a = ((const float4*)(nei_rel_mem + base))[q];
                    float4 h = ((const float4*)(head_rel_emb + hb))[q];
                    val.x = __fadd_rn(a.x, h.x);
                    val.y = __fadd_rn(a.y, h.y);
                    val.z = __fadd_rn(a.z, h.z);
                    val.w = __fadd_rn(a.w, h.w);
                }
            } else {
                const float4* p = (const float4*)((rel ? head_rel_emb : head_emb) + hb);
                val = p[q];
            }
        }
        float* dst = out + (rel ? o_rel : o_node) + ((size_t)n * C_ + j) * R_;
        ((float4*)dst)[q] = val;
    }
}

extern "C" void kernel_launch(void* const* d_in, const int* in_sizes, int n_in,
                              void* d_out, int out_size, void* d_ws, size_t ws_size,
                              hipStream_t stream) {
    const float* curr_emb      = (const float*)d_in[0];
    const float* alpha         = (const float*)d_in[1];
    const float* msg           = (const float*)d_in[2];
    const float* curr_node_mem = (const float*)d_in[3];
    const float* curr_rel_mem  = (const float*)d_in[4];
    const float* nei_node_mem  = (const float*)d_in[5];
    const float* nei_rel_mem   = (const float*)d_in[6];
    const float* head_rel_emb  = (const float*)d_in[7];
    const float* head_emb      = (const float*)d_in[8];
    float* out = (float*)d_out;

    const int N = in_sizes[1] / D_;   // alpha is (N, D, 1)

    memagg_kernel<<<N, 256, 0, stream>>>(curr_emb, alpha, msg,
                                         curr_node_mem, curr_rel_mem,
                                         nei_node_mem, nei_rel_mem,
                                         head_rel_emb, head_emb,
                                         out, N);
}